// Round 1
// baseline (339.872 us; speedup 1.0000x reference)
//
#include <hip/hip_runtime.h>

#define AD 32
#define HID 16
#define IN_DIM 33

static inline int imin_host(int a, int b) { return a < b ? a : b; }

__device__ __forceinline__ float sigmoidf_fast(float x) {
    return 1.0f / (1.0f + __expf(-x));
}

// Phase 1: hpre[a][j] = sum_i emb[a][i] * W1[j][i]   (cols 0..31 only)
__global__ __launch_bounds__(256) void atom_pre_kernel(
    const float* __restrict__ emb,   // [N,32]
    const float* __restrict__ W1,    // [16,33] row-major (out,in)
    float* __restrict__ hpre,        // [N,16]
    int N)
{
    int stride = gridDim.x * blockDim.x;
    for (int a = blockIdx.x * blockDim.x + threadIdx.x; a < N; a += stride) {
        const float4* e4 = reinterpret_cast<const float4*>(emb + (size_t)a * AD);
        float x[AD];
#pragma unroll
        for (int q = 0; q < AD / 4; ++q) {
            float4 v = e4[q];
            x[4*q+0] = v.x; x[4*q+1] = v.y; x[4*q+2] = v.z; x[4*q+3] = v.w;
        }
        float4* out4 = reinterpret_cast<float4*>(hpre + (size_t)a * HID);
#pragma unroll
        for (int q = 0; q < HID / 4; ++q) {
            float4 o;
            float* op = &o.x;
#pragma unroll
            for (int r = 0; r < 4; ++r) {
                const int j = 4*q + r;
                float s = 0.0f;
#pragma unroll
                for (int i = 0; i < AD; ++i)
                    s = fmaf(x[i], W1[j*IN_DIM + i], s);
                op[r] = s;
            }
            out4[q] = o;
        }
    }
}

// Phase 2: per output pair (e, e+half): gather hpre rows, finish MLP, sigmoid, avg.
__global__ __launch_bounds__(256) void edge_kernel(
    const float* __restrict__ hpre,    // [N,16]
    const int* __restrict__ eidx,      // [2,E]
    const float* __restrict__ benergy, // [E]
    const float* __restrict__ W1,      // [16,33] (need col 32)
    const float* __restrict__ b1,      // [16]
    const float* __restrict__ W2,      // [16]
    const float* __restrict__ b2,      // [1]
    const float* __restrict__ We,      // [1]
    const float* __restrict__ be,      // [1]
    float* __restrict__ out,           // [half]
    int E, int half)
{
    // Wave-uniform weight loads -> compiler scalarizes into SGPRs.
    float w1c[HID], bb1[HID], w2[HID];
#pragma unroll
    for (int j = 0; j < HID; ++j) {
        w1c[j] = W1[j*IN_DIM + 32];
        bb1[j] = b1[j];
        w2[j]  = W2[j];
    }
    const float wb2 = b2[0];
    const float we  = We[0];
    const float bee = be[0];

    int stride = gridDim.x * blockDim.x;
    for (int t = blockIdx.x * blockDim.x + threadIdx.x; t < half; t += stride) {
        float sc[2];
#pragma unroll
        for (int k = 0; k < 2; ++k) {
            const int e = t + k * half;
            const int src = eidx[e];
            const int dst = eidx[E + e];
            const float energy = fmaf(benergy[e], we, bee);
            const float4* s4 = reinterpret_cast<const float4*>(hpre + (size_t)src * HID);
            const float4* d4 = reinterpret_cast<const float4*>(hpre + (size_t)dst * HID);
            float logit = wb2;
#pragma unroll
            for (int q = 0; q < HID / 4; ++q) {
                float4 a = s4[q];
                float4 b = d4[q];
                float h0 = a.x + b.x + fmaf(energy, w1c[4*q+0], bb1[4*q+0]);
                float h1 = a.y + b.y + fmaf(energy, w1c[4*q+1], bb1[4*q+1]);
                float h2 = a.z + b.z + fmaf(energy, w1c[4*q+2], bb1[4*q+2]);
                float h3 = a.w + b.w + fmaf(energy, w1c[4*q+3], bb1[4*q+3]);
                logit = fmaf(w2[4*q+0], fmaxf(h0, 0.0f), logit);
                logit = fmaf(w2[4*q+1], fmaxf(h1, 0.0f), logit);
                logit = fmaf(w2[4*q+2], fmaxf(h2, 0.0f), logit);
                logit = fmaf(w2[4*q+3], fmaxf(h3, 0.0f), logit);
            }
            sc[k] = sigmoidf_fast(logit);
        }
        out[t] = 0.5f * (sc[0] + sc[1]);
    }
}

// Fallback (workspace too small): fully fused, gathers raw 32-float embeddings.
__global__ __launch_bounds__(256) void fused_kernel(
    const float* __restrict__ emb,     // [N,32]
    const int* __restrict__ eidx,      // [2,E]
    const float* __restrict__ benergy, // [E]
    const float* __restrict__ W1, const float* __restrict__ b1,
    const float* __restrict__ W2, const float* __restrict__ b2,
    const float* __restrict__ We, const float* __restrict__ be,
    float* __restrict__ out, int E, int half)
{
    const float we  = We[0];
    const float bee = be[0];
    const float wb2 = b2[0];
    int stride = gridDim.x * blockDim.x;
    for (int t = blockIdx.x * blockDim.x + threadIdx.x; t < half; t += stride) {
        float sc[2];
#pragma unroll
        for (int k = 0; k < 2; ++k) {
            const int e = t + k * half;
            const int src = eidx[e];
            const int dst = eidx[E + e];
            const float4* s4 = reinterpret_cast<const float4*>(emb + (size_t)src * AD);
            const float4* d4 = reinterpret_cast<const float4*>(emb + (size_t)dst * AD);
            float feat[AD];
#pragma unroll
            for (int q = 0; q < AD / 4; ++q) {
                float4 a = s4[q];
                float4 b = d4[q];
                feat[4*q+0] = a.x + b.x;
                feat[4*q+1] = a.y + b.y;
                feat[4*q+2] = a.z + b.z;
                feat[4*q+3] = a.w + b.w;
            }
            const float energy = fmaf(benergy[e], we, bee);
            float logit = wb2;
#pragma unroll
            for (int j = 0; j < HID; ++j) {
                float s = fmaf(energy, W1[j*IN_DIM + 32], b1[j]);
#pragma unroll
                for (int i = 0; i < AD; ++i)
                    s = fmaf(feat[i], W1[j*IN_DIM + i], s);
                logit = fmaf(W2[j], fmaxf(s, 0.0f), logit);
            }
            sc[k] = sigmoidf_fast(logit);
        }
        out[t] = 0.5f * (sc[0] + sc[1]);
    }
}

extern "C" void kernel_launch(void* const* d_in, const int* in_sizes, int n_in,
                              void* d_out, int out_size, void* d_ws, size_t ws_size,
                              hipStream_t stream) {
    const float* emb     = (const float*)d_in[0];
    const float* benergy = (const float*)d_in[1];
    const float* We      = (const float*)d_in[2];
    const float* be      = (const float*)d_in[3];
    const float* W1      = (const float*)d_in[4];
    const float* b1      = (const float*)d_in[5];
    const float* W2      = (const float*)d_in[6];
    const float* b2      = (const float*)d_in[7];
    const int*   eidx    = (const int*)d_in[8];
    float* out = (float*)d_out;

    const int N    = in_sizes[0] / AD;
    const int E    = in_sizes[1];
    const int half = out_size;   // E/2

    const size_t need = (size_t)N * HID * sizeof(float);
    if (ws_size >= need) {
        float* hpre = (float*)d_ws;
        const int blocks1 = imin_host((N + 255) / 256, 2048);
        atom_pre_kernel<<<blocks1, 256, 0, stream>>>(emb, W1, hpre, N);
        const int blocks2 = imin_host((half + 255) / 256, 2048);
        edge_kernel<<<blocks2, 256, 0, stream>>>(hpre, eidx, benergy,
                                                 W1, b1, W2, b2, We, be,
                                                 out, E, half);
    } else {
        const int blocks = imin_host((half + 255) / 256, 2048);
        fused_kernel<<<blocks, 256, 0, stream>>>(emb, eidx, benergy,
                                                 W1, b1, W2, b2, We, be,
                                                 out, E, half);
    }
}

// Round 2
// 217.647 us; speedup vs baseline: 1.5616x; 1.5616x over previous
//
#include <hip/hip_runtime.h>
#include <hip/hip_fp16.h>

#define AD 32
#define HID 16
#define IN_DIM 33

typedef float f32x4 __attribute__((ext_vector_type(4)));

union VU {
    f32x4 v;
    __half2 h[4];
};

static inline int imin_host(int a, int b) { return a < b ? a : b; }

__device__ __forceinline__ float sigmoidf_fast(float x) {
    return 1.0f / (1.0f + __expf(-x));
}

// Phase 1: hpre[a][j] = sum_i emb[a][i] * W1[j][i]  (cols 0..31), stored fp16.
__global__ __launch_bounds__(256) void atom_pre_kernel(
    const float* __restrict__ emb,   // [N,32]
    const float* __restrict__ W1,    // [16,33] row-major (out,in)
    __half* __restrict__ hpre,       // [N,16] fp16
    int N)
{
    int a = blockIdx.x * blockDim.x + threadIdx.x;
    if (a >= N) return;

    const f32x4* e4 = reinterpret_cast<const f32x4*>(emb + (size_t)a * AD);
    float x[AD];
#pragma unroll
    for (int q = 0; q < AD / 4; ++q) {
        f32x4 v = __builtin_nontemporal_load(&e4[q]);
        x[4*q+0] = v.x; x[4*q+1] = v.y; x[4*q+2] = v.z; x[4*q+3] = v.w;
    }

    float s[HID];
#pragma unroll
    for (int j = 0; j < HID; ++j) {
        float acc = 0.0f;
#pragma unroll
        for (int i = 0; i < AD; ++i)
            acc = fmaf(x[i], W1[j*IN_DIM + i], acc);
        s[j] = acc;
    }

    VU a0, a1;
#pragma unroll
    for (int q = 0; q < 4; ++q) a0.h[q] = __floats2half2_rn(s[2*q],   s[2*q+1]);
#pragma unroll
    for (int q = 0; q < 4; ++q) a1.h[q] = __floats2half2_rn(s[8+2*q], s[8+2*q+1]);

    f32x4* o4 = reinterpret_cast<f32x4*>(hpre + (size_t)a * HID);
    o4[0] = a0.v;
    o4[1] = a1.v;
}

// Phase 2: one output per thread. Issue all gathers up-front, then compute.
__global__ __launch_bounds__(256) void edge_kernel(
    const __half* __restrict__ hpre,   // [N,16] fp16
    const int* __restrict__ eidx,      // [2,E]
    const float* __restrict__ benergy, // [E]
    const float* __restrict__ W1,      // [16,33] (need col 32)
    const float* __restrict__ b1,      // [16]
    const float* __restrict__ W2,      // [16]
    const float* __restrict__ b2,      // [1]
    const float* __restrict__ We,      // [1]
    const float* __restrict__ be,      // [1]
    float* __restrict__ out,           // [half]
    int E, int half)
{
    // Wave-uniform weight loads -> scalarized into SGPRs.
    float w1c[HID], bb1[HID], w2[HID];
#pragma unroll
    for (int j = 0; j < HID; ++j) {
        w1c[j] = W1[j*IN_DIM + 32];
        bb1[j] = b1[j];
        w2[j]  = W2[j];
    }
    const float wb2 = b2[0];
    const float we  = We[0];
    const float bee = be[0];

    const int t = blockIdx.x * blockDim.x + threadIdx.x;
    if (t >= half) return;

    const int e0 = t;
    const int e1 = t + half;

    // Stream loads (nontemporal: don't pollute L2 -- keep it for the table).
    const int s0 = __builtin_nontemporal_load(&eidx[e0]);
    const int d0 = __builtin_nontemporal_load(&eidx[E + e0]);
    const int s1 = __builtin_nontemporal_load(&eidx[e1]);
    const int d1 = __builtin_nontemporal_load(&eidx[E + e1]);
    const float ben0 = __builtin_nontemporal_load(&benergy[e0]);
    const float ben1 = __builtin_nontemporal_load(&benergy[e1]);

    // 4 row gathers x 2 x 16B, all independent -> all in flight together.
    const f32x4* rs0 = reinterpret_cast<const f32x4*>(hpre + (size_t)s0 * HID);
    const f32x4* rd0 = reinterpret_cast<const f32x4*>(hpre + (size_t)d0 * HID);
    const f32x4* rs1 = reinterpret_cast<const f32x4*>(hpre + (size_t)s1 * HID);
    const f32x4* rd1 = reinterpret_cast<const f32x4*>(hpre + (size_t)d1 * HID);

    f32x4 g0 = rs0[0], g1 = rs0[1];
    f32x4 g2 = rd0[0], g3 = rd0[1];
    f32x4 g4 = rs1[0], g5 = rs1[1];
    f32x4 g6 = rd1[0], g7 = rd1[1];

    float en[2];
    en[0] = fmaf(ben0, we, bee);
    en[1] = fmaf(ben1, we, bee);

    float sc[2];
#pragma unroll
    for (int k = 0; k < 2; ++k) {
        VU us0, us1, ud0, ud1;
        if (k == 0) { us0.v = g0; us1.v = g1; ud0.v = g2; ud1.v = g3; }
        else        { us0.v = g4; us1.v = g5; ud0.v = g6; ud1.v = g7; }

        float logit = wb2;
#pragma unroll
        for (int q = 0; q < 4; ++q) {
            float2 sf = __half22float2(__hadd2(us0.h[q], ud0.h[q]));
            const int j = 2*q;
            float h0 = sf.x + fmaf(en[k], w1c[j],   bb1[j]);
            float h1 = sf.y + fmaf(en[k], w1c[j+1], bb1[j+1]);
            logit = fmaf(w2[j],   fmaxf(h0, 0.0f), logit);
            logit = fmaf(w2[j+1], fmaxf(h1, 0.0f), logit);
        }
#pragma unroll
        for (int q = 0; q < 4; ++q) {
            float2 sf = __half22float2(__hadd2(us1.h[q], ud1.h[q]));
            const int j = 8 + 2*q;
            float h0 = sf.x + fmaf(en[k], w1c[j],   bb1[j]);
            float h1 = sf.y + fmaf(en[k], w1c[j+1], bb1[j+1]);
            logit = fmaf(w2[j],   fmaxf(h0, 0.0f), logit);
            logit = fmaf(w2[j+1], fmaxf(h1, 0.0f), logit);
        }
        sc[k] = sigmoidf_fast(logit);
    }
    out[t] = 0.5f * (sc[0] + sc[1]);
}

// Fallback (workspace too small): fully fused fp32, gathers raw embeddings.
__global__ __launch_bounds__(256) void fused_kernel(
    const float* __restrict__ emb,
    const int* __restrict__ eidx,
    const float* __restrict__ benergy,
    const float* __restrict__ W1, const float* __restrict__ b1,
    const float* __restrict__ W2, const float* __restrict__ b2,
    const float* __restrict__ We, const float* __restrict__ be,
    float* __restrict__ out, int E, int half)
{
    const float we  = We[0];
    const float bee = be[0];
    const float wb2 = b2[0];
    int stride = gridDim.x * blockDim.x;
    for (int t = blockIdx.x * blockDim.x + threadIdx.x; t < half; t += stride) {
        float sc[2];
#pragma unroll
        for (int k = 0; k < 2; ++k) {
            const int e = t + k * half;
            const int src = eidx[e];
            const int dst = eidx[E + e];
            const float4* s4 = reinterpret_cast<const float4*>(emb + (size_t)src * AD);
            const float4* d4 = reinterpret_cast<const float4*>(emb + (size_t)dst * AD);
            float feat[AD];
#pragma unroll
            for (int q = 0; q < AD / 4; ++q) {
                float4 a = s4[q];
                float4 b = d4[q];
                feat[4*q+0] = a.x + b.x;
                feat[4*q+1] = a.y + b.y;
                feat[4*q+2] = a.z + b.z;
                feat[4*q+3] = a.w + b.w;
            }
            const float energy = fmaf(benergy[e], we, bee);
            float logit = wb2;
#pragma unroll
            for (int j = 0; j < HID; ++j) {
                float s = fmaf(energy, W1[j*IN_DIM + 32], b1[j]);
#pragma unroll
                for (int i = 0; i < AD; ++i)
                    s = fmaf(feat[i], W1[j*IN_DIM + i], s);
                logit = fmaf(W2[j], fmaxf(s, 0.0f), logit);
            }
            sc[k] = sigmoidf_fast(logit);
        }
        out[t] = 0.5f * (sc[0] + sc[1]);
    }
}

extern "C" void kernel_launch(void* const* d_in, const int* in_sizes, int n_in,
                              void* d_out, int out_size, void* d_ws, size_t ws_size,
                              hipStream_t stream) {
    const float* emb     = (const float*)d_in[0];
    const float* benergy = (const float*)d_in[1];
    const float* We      = (const float*)d_in[2];
    const float* be      = (const float*)d_in[3];
    const float* W1      = (const float*)d_in[4];
    const float* b1      = (const float*)d_in[5];
    const float* W2      = (const float*)d_in[6];
    const float* b2      = (const float*)d_in[7];
    const int*   eidx    = (const int*)d_in[8];
    float* out = (float*)d_out;

    const int N    = in_sizes[0] / AD;
    const int E    = in_sizes[1];
    const int half = out_size;   // E/2

    const size_t need = (size_t)N * HID * sizeof(__half);
    if (ws_size >= need) {
        __half* hpre = (__half*)d_ws;
        const int blocks1 = (N + 255) / 256;
        atom_pre_kernel<<<blocks1, 256, 0, stream>>>(emb, W1, hpre, N);
        const int blocks2 = (half + 255) / 256;
        edge_kernel<<<blocks2, 256, 0, stream>>>(hpre, eidx, benergy,
                                                 W1, b1, W2, b2, We, be,
                                                 out, E, half);
    } else {
        const int blocks = imin_host((half + 255) / 256, 2048);
        fused_kernel<<<blocks, 256, 0, stream>>>(emb, eidx, benergy,
                                                 W1, b1, W2, b2, We, be,
                                                 out, E, half);
    }
}

// Round 3
// 159.974 us; speedup vs baseline: 2.1245x; 1.3605x over previous
//
#include <hip/hip_runtime.h>
#include <hip/hip_fp16.h>

#define AD 32
#define HID 16
#define IN_DIM 33

typedef float f32x4 __attribute__((ext_vector_type(4)));

union VU {
    f32x4 v;
    __half2 h[4];
};

static inline int imin_host(int a, int b) { return a < b ? a : b; }

__device__ __forceinline__ float sigmoidf_fast(float x) {
    return 1.0f / (1.0f + __expf(-x));
}

// Phase 1: hpre[a][j] = sum_i emb[a][i] * W1[j][i]  (cols 0..31), stored fp16.
// Plain cached loads: each thread reads its 128B row via 8 x float4; the L1/L2
// line fill is reused across the 8 loads (NT broke this in round 2).
__global__ __launch_bounds__(256) void atom_pre_kernel(
    const float* __restrict__ emb,   // [N,32]
    const float* __restrict__ W1,    // [16,33] row-major (out,in)
    __half* __restrict__ hpre,       // [N,16] fp16
    int N)
{
    int a = blockIdx.x * blockDim.x + threadIdx.x;
    if (a >= N) return;

    const f32x4* e4 = reinterpret_cast<const f32x4*>(emb + (size_t)a * AD);
    float x[AD];
#pragma unroll
    for (int q = 0; q < AD / 4; ++q) {
        f32x4 v = e4[q];
        x[4*q+0] = v.x; x[4*q+1] = v.y; x[4*q+2] = v.z; x[4*q+3] = v.w;
    }

    float s[HID];
#pragma unroll
    for (int j = 0; j < HID; ++j) {
        float acc = 0.0f;
#pragma unroll
        for (int i = 0; i < AD; ++i)
            acc = fmaf(x[i], W1[j*IN_DIM + i], acc);
        s[j] = acc;
    }

    VU a0, a1;
#pragma unroll
    for (int q = 0; q < 4; ++q) a0.h[q] = __floats2half2_rn(s[2*q],   s[2*q+1]);
#pragma unroll
    for (int q = 0; q < 4; ++q) a1.h[q] = __floats2half2_rn(s[8+2*q], s[8+2*q+1]);

    f32x4* o4 = reinterpret_cast<f32x4*>(hpre + (size_t)a * HID);
    __builtin_nontemporal_store(a0.v, &o4[0]);
    __builtin_nontemporal_store(a1.v, &o4[1]);
}

// Phase 2: one output per thread. Issue all gathers up-front, then compute.
__global__ __launch_bounds__(256) void edge_kernel(
    const __half* __restrict__ hpre,   // [N,16] fp16
    const int* __restrict__ eidx,      // [2,E]
    const float* __restrict__ benergy, // [E]
    const float* __restrict__ W1,      // [16,33] (need col 32)
    const float* __restrict__ b1,      // [16]
    const float* __restrict__ W2,      // [16]
    const float* __restrict__ b2,      // [1]
    const float* __restrict__ We,      // [1]
    const float* __restrict__ be,      // [1]
    float* __restrict__ out,           // [half]
    int E, int half)
{
    // Wave-uniform weight loads -> scalarized into SGPRs.
    float w1c[HID], bb1[HID], w2[HID];
#pragma unroll
    for (int j = 0; j < HID; ++j) {
        w1c[j] = W1[j*IN_DIM + 32];
        bb1[j] = b1[j];
        w2[j]  = W2[j];
    }
    const float wb2 = b2[0];
    const float we  = We[0];
    const float bee = be[0];

    const int t = blockIdx.x * blockDim.x + threadIdx.x;
    if (t >= half) return;

    const int e0 = t;
    const int e1 = t + half;

    // Stream loads (nontemporal: single-use, keep L2 for the table).
    const int s0 = __builtin_nontemporal_load(&eidx[e0]);
    const int d0 = __builtin_nontemporal_load(&eidx[E + e0]);
    const int s1 = __builtin_nontemporal_load(&eidx[e1]);
    const int d1 = __builtin_nontemporal_load(&eidx[E + e1]);
    const float ben0 = __builtin_nontemporal_load(&benergy[e0]);
    const float ben1 = __builtin_nontemporal_load(&benergy[e1]);

    // 4 row gathers x 2 x 16B, all independent -> all in flight together.
    const f32x4* rs0 = reinterpret_cast<const f32x4*>(hpre + (size_t)s0 * HID);
    const f32x4* rd0 = reinterpret_cast<const f32x4*>(hpre + (size_t)d0 * HID);
    const f32x4* rs1 = reinterpret_cast<const f32x4*>(hpre + (size_t)s1 * HID);
    const f32x4* rd1 = reinterpret_cast<const f32x4*>(hpre + (size_t)d1 * HID);

    f32x4 g0 = rs0[0], g1 = rs0[1];
    f32x4 g2 = rd0[0], g3 = rd0[1];
    f32x4 g4 = rs1[0], g5 = rs1[1];
    f32x4 g6 = rd1[0], g7 = rd1[1];

    float en[2];
    en[0] = fmaf(ben0, we, bee);
    en[1] = fmaf(ben1, we, bee);

    float sc[2];
#pragma unroll
    for (int k = 0; k < 2; ++k) {
        VU us0, us1, ud0, ud1;
        if (k == 0) { us0.v = g0; us1.v = g1; ud0.v = g2; ud1.v = g3; }
        else        { us0.v = g4; us1.v = g5; ud0.v = g6; ud1.v = g7; }

        float logit = wb2;
#pragma unroll
        for (int q = 0; q < 4; ++q) {
            float2 sf = __half22float2(__hadd2(us0.h[q], ud0.h[q]));
            const int j = 2*q;
            float h0 = sf.x + fmaf(en[k], w1c[j],   bb1[j]);
            float h1 = sf.y + fmaf(en[k], w1c[j+1], bb1[j+1]);
            logit = fmaf(w2[j],   fmaxf(h0, 0.0f), logit);
            logit = fmaf(w2[j+1], fmaxf(h1, 0.0f), logit);
        }
#pragma unroll
        for (int q = 0; q < 4; ++q) {
            float2 sf = __half22float2(__hadd2(us1.h[q], ud1.h[q]));
            const int j = 8 + 2*q;
            float h0 = sf.x + fmaf(en[k], w1c[j],   bb1[j]);
            float h1 = sf.y + fmaf(en[k], w1c[j+1], bb1[j+1]);
            logit = fmaf(w2[j],   fmaxf(h0, 0.0f), logit);
            logit = fmaf(w2[j+1], fmaxf(h1, 0.0f), logit);
        }
        sc[k] = sigmoidf_fast(logit);
    }
    __builtin_nontemporal_store(0.5f * (sc[0] + sc[1]), &out[t]);
}

// Fallback (workspace too small): fully fused fp32, gathers raw embeddings.
__global__ __launch_bounds__(256) void fused_kernel(
    const float* __restrict__ emb,
    const int* __restrict__ eidx,
    const float* __restrict__ benergy,
    const float* __restrict__ W1, const float* __restrict__ b1,
    const float* __restrict__ W2, const float* __restrict__ b2,
    const float* __restrict__ We, const float* __restrict__ be,
    float* __restrict__ out, int E, int half)
{
    const float we  = We[0];
    const float bee = be[0];
    const float wb2 = b2[0];
    int stride = gridDim.x * blockDim.x;
    for (int t = blockIdx.x * blockDim.x + threadIdx.x; t < half; t += stride) {
        float sc[2];
#pragma unroll
        for (int k = 0; k < 2; ++k) {
            const int e = t + k * half;
            const int src = eidx[e];
            const int dst = eidx[E + e];
            const float4* s4 = reinterpret_cast<const float4*>(emb + (size_t)src * AD);
            const float4* d4 = reinterpret_cast<const float4*>(emb + (size_t)dst * AD);
            float feat[AD];
#pragma unroll
            for (int q = 0; q < AD / 4; ++q) {
                float4 a = s4[q];
                float4 b = d4[q];
                feat[4*q+0] = a.x + b.x;
                feat[4*q+1] = a.y + b.y;
                feat[4*q+2] = a.z + b.z;
                feat[4*q+3] = a.w + b.w;
            }
            const float energy = fmaf(benergy[e], we, bee);
            float logit = wb2;
#pragma unroll
            for (int j = 0; j < HID; ++j) {
                float s = fmaf(energy, W1[j*IN_DIM + 32], b1[j]);
#pragma unroll
                for (int i = 0; i < AD; ++i)
                    s = fmaf(feat[i], W1[j*IN_DIM + i], s);
                logit = fmaf(W2[j], fmaxf(s, 0.0f), logit);
            }
            sc[k] = sigmoidf_fast(logit);
        }
        out[t] = 0.5f * (sc[0] + sc[1]);
    }
}

extern "C" void kernel_launch(void* const* d_in, const int* in_sizes, int n_in,
                              void* d_out, int out_size, void* d_ws, size_t ws_size,
                              hipStream_t stream) {
    const float* emb     = (const float*)d_in[0];
    const float* benergy = (const float*)d_in[1];
    const float* We      = (const float*)d_in[2];
    const float* be      = (const float*)d_in[3];
    const float* W1      = (const float*)d_in[4];
    const float* b1      = (const float*)d_in[5];
    const float* W2      = (const float*)d_in[6];
    const float* b2      = (const float*)d_in[7];
    const int*   eidx    = (const int*)d_in[8];
    float* out = (float*)d_out;

    const int N    = in_sizes[0] / AD;
    const int E    = in_sizes[1];
    const int half = out_size;   // E/2

    const size_t need = (size_t)N * HID * sizeof(__half);
    if (ws_size >= need) {
        __half* hpre = (__half*)d_ws;
        const int blocks1 = (N + 255) / 256;
        atom_pre_kernel<<<blocks1, 256, 0, stream>>>(emb, W1, hpre, N);
        const int blocks2 = (half + 255) / 256;
        edge_kernel<<<blocks2, 256, 0, stream>>>(hpre, eidx, benergy,
                                                 W1, b1, W2, b2, We, be,
                                                 out, E, half);
    } else {
        const int blocks = imin_host((half + 255) / 256, 2048);
        fused_kernel<<<blocks, 256, 0, stream>>>(emb, eidx, benergy,
                                                 W1, b1, W2, b2, We, be,
                                                 out, E, half);
    }
}